// Round 1
// 667.789 us; speedup vs baseline: 1.0095x; 1.0095x over previous
//
#include <hip/hip_runtime.h>

// Reference collapse analysis (verified earlier, absmax 0.03 vs thr 0.27):
//   x[:,None,:] -> conv input (N=8192, W=1, C=16384): spatial length 1.
//   Conv k=2, dilation d, SAME: taps at {0,d}, sample at d//2.
//     d=1: c1[b] = dot(x[b], w1[0,:,0]) + b1;  d=4,8,32,128: c_i = b_i (const).
//   => out[b,j] = (dot(x[b], w1[0]) + b1+b2+b3+b4+b5) * wd[j] + bd[j]
// Memory-bound: stream 512 MiB of x once. Floor ~85 us @ 6.3 TB/s.
//
// Round-4 restructure: one block per row; w1 preloaded into registers once
// per block (L2-hot, identical across rows), so the steady-state vmcnt FIFO
// contains ONLY nontemporal x loads -> 16 loads (16 KB) in flight per wave.
// Previous version interleaved L2-hit w loads with HBM x loads in the same
// in-order queue, forcing shallow counted waits (~1.6 TB/s effective).

constexpr int L    = 16384;
constexpr int OUTD = 128;
constexpr int VPT  = 16;   // fx4 vectors per thread: 4096 fx4 per row / 256 threads

typedef float fx4 __attribute__((ext_vector_type(4)));

__global__ __launch_bounds__(256, 2)
void audio_collapse_kernel(const float* __restrict__ x,    // (B, L)
                           const float* __restrict__ w1,   // (2, L, 1); first L used
                           const float* __restrict__ b1,
                           const float* __restrict__ b2,
                           const float* __restrict__ b3,
                           const float* __restrict__ b4,
                           const float* __restrict__ b5,
                           const float* __restrict__ wd,   // (1, 128)
                           const float* __restrict__ bd,   // (128,)
                           float* __restrict__ out,        // (B, 128)
                           int B)
{
    const int tid = threadIdx.x;
    const int row = blockIdx.x;
    if (row >= B) return;

    const fx4* __restrict__ xr = (const fx4*)(x + (size_t)row * L);
    const fx4* __restrict__ wr = (const fx4*)(w1);   // w1[0,:,0] contiguous

    // Preload this thread's 16 w vectors into registers. Same addresses for
    // every block -> L2-resident; paid once per row, outside the hot loop.
    fx4 wv[VPT];
    #pragma unroll
    for (int k = 0; k < VPT; ++k)
        wv[k] = wr[k * 256 + tid];

    // Issue all 16 x loads (nontemporal streaming; x is read exactly once).
    // Pure-x vmcnt FIFO: nothing forces an early drain, so the wave keeps
    // up to 16 KB of HBM reads in flight.
    fx4 xv[VPT];
    #pragma unroll
    for (int k = 0; k < VPT; ++k)
        xv[k] = __builtin_nontemporal_load(&xr[k * 256 + tid]);

    float acc = 0.f;
    #pragma unroll
    for (int k = 0; k < VPT; ++k)
        acc += xv[k].x * wv[k].x + xv[k].y * wv[k].y
             + xv[k].z * wv[k].z + xv[k].w * wv[k].w;

    // Butterfly reduce across the 64-lane wave.
    #pragma unroll
    for (int off = 32; off > 0; off >>= 1)
        acc += __shfl_xor(acc, off, 64);

    // Cross-wave reduce (4 waves) through LDS.
    __shared__ float wsum[4];
    const int wave = tid >> 6;
    const int lane = tid & 63;
    if (lane == 0) wsum[wave] = acc;
    __syncthreads();

    const float y = (wsum[0] + wsum[1]) + (wsum[2] + wsum[3])
                  + b1[0] + b2[0] + b3[0] + b4[0] + b5[0];

    // Epilogue: out[row, j] = y * wd[j] + bd[j]; threads 0..127 write one each.
    if (tid < OUTD) {
        float* __restrict__ orow = out + (size_t)row * OUTD;
        __builtin_nontemporal_store(fmaf(y, wd[tid], bd[tid]), &orow[tid]);
    }
}

extern "C" void kernel_launch(void* const* d_in, const int* in_sizes, int n_in,
                              void* d_out, int out_size, void* d_ws, size_t ws_size,
                              hipStream_t stream) {
    const float* x  = (const float*)d_in[0];
    const float* w1 = (const float*)d_in[1];
    const float* b1 = (const float*)d_in[2];
    const float* b2 = (const float*)d_in[4];
    const float* b3 = (const float*)d_in[6];
    const float* b4 = (const float*)d_in[8];
    const float* b5 = (const float*)d_in[10];
    const float* wd = (const float*)d_in[11];
    const float* bd = (const float*)d_in[12];
    float* out = (float*)d_out;

    const int B = in_sizes[0] / L;   // 8192 (in_sizes in elements)

    audio_collapse_kernel<<<B, 256, 0, stream>>>(
        x, w1, b1, b2, b3, b4, b5, wd, bd, out, B);
}